// Round 8
// baseline (491.669 us; speedup 1.0000x reference)
//
#include <hip/hip_runtime.h>

#define VOCAB 50257
#define EMBED 128
#define NTOK  (64 * 4096)
#define NSLICE 8            // 8 slices x 16 embed dims; slice s <-> XCD s
#define NBLK  (NTOK / 64)   // 4096 token-blocks per slice

typedef float    f32x4 __attribute__((ext_vector_type(4)));
typedef _Float16 f16x4 __attribute__((ext_vector_type(4)));
typedef _Float16 f16x8 __attribute__((ext_vector_type(8)));

// Pass 1: slice-major fp16 table with bias folded:
//   Wt[s][v][e'] = (half)(W[s*16+e'][v] + bias[s*16+e'])
__global__ void transpose_h_kernel(const float* __restrict__ W,
                                   const float* __restrict__ bias,
                                   _Float16* __restrict__ Wt) {
    __shared__ float tile[64][65];   // [v_loc][e_loc], +1 pad
    const int t  = threadIdx.x;
    const int v0 = blockIdx.x * 64;
    const int e0 = blockIdx.y * 64;
    const bool full = (v0 + 64 <= VOCAB);

    if (full) {
#pragma unroll
        for (int it = 0; it < 4; ++it) {
            const int e_loc = (t >> 4) + it * 16;
            const int c4    = (t & 15) * 4;
            f32x4 val = *(const f32x4*)&W[(size_t)(e0 + e_loc) * VOCAB + v0 + c4];
            tile[c4 + 0][e_loc] = val.x;
            tile[c4 + 1][e_loc] = val.y;
            tile[c4 + 2][e_loc] = val.z;
            tile[c4 + 3][e_loc] = val.w;
        }
    } else {
#pragma unroll
        for (int it = 0; it < 16; ++it) {
            const int e_loc = (t >> 6) + it * 4;
            const int c     = t & 63;
            const int v     = v0 + c;
            tile[c][e_loc] = (v < VOCAB) ? W[(size_t)(e0 + e_loc) * VOCAB + v]
                                         : 0.0f;
        }
    }
    __syncthreads();

    const int eo = (t & 7) * 8;
    const int eg = e0 + eo;
    const int s  = eg >> 4;
    const int ep = eg & 15;
    const f32x4 ba = *(const f32x4*)&bias[eg];
    const f32x4 bb = *(const f32x4*)&bias[eg + 4];
#pragma unroll
    for (int it = 0; it < 2; ++it) {
        const int v_loc = (t >> 3) + it * 32;
        const int v     = v0 + v_loc;
        if (v < VOCAB) {
            f16x8 h;
            h[0] = (_Float16)(tile[v_loc][eo + 0] + ba.x);
            h[1] = (_Float16)(tile[v_loc][eo + 1] + ba.y);
            h[2] = (_Float16)(tile[v_loc][eo + 2] + ba.z);
            h[3] = (_Float16)(tile[v_loc][eo + 3] + ba.w);
            h[4] = (_Float16)(tile[v_loc][eo + 4] + bb.x);
            h[5] = (_Float16)(tile[v_loc][eo + 5] + bb.y);
            h[6] = (_Float16)(tile[v_loc][eo + 6] + bb.z);
            h[7] = (_Float16)(tile[v_loc][eo + 7] + bb.w);
            *(f16x8*)&Wt[((size_t)s * VOCAB + v) * 16 + ep] = h;
        }
    }
}

// Zero the 8 per-slice work-queue counters (graph-capture-safe init).
__global__ void zero_ctr_kernel(unsigned* ctr) {
    if (threadIdx.x < NSLICE) ctr[threadIdx.x] = 0;
}

// Pass 2: XCD-affine sliced gather. Each block reads its physical XCD id
// (HW_REG_XCC_ID, verified gfx950) and processes ONLY that XCD's slice,
// pulling 64-token work items from a per-slice device-scope atomic queue.
// => every table read on XCD k touches a contiguous 1.6 MB slice, fitting
// the 4 MB per-XCD L2 by construction. Deterministic: each (slice,tblk)
// done exactly once, disjoint output writes.
__global__ void gather_xcd_kernel(const int* __restrict__ x,
                                  const f16x4* __restrict__ Wt,
                                  f32x4* __restrict__ out,
                                  unsigned* __restrict__ ctr) {
    unsigned xcd;
    asm volatile("s_getreg_b32 %0, hwreg(HW_REG_XCC_ID)" : "=s"(xcd));
    const int slice = (int)(xcd & (NSLICE - 1));
    const int t  = threadIdx.x;
    const int lq = t & 3;        // f16x4 quad within the 16-dim slice
    const int lt = t >> 2;       // token 0..63 within the work item

    __shared__ unsigned s_tblk;
    for (;;) {
        if (t == 0) s_tblk = atomicAdd(&ctr[slice], 1u);
        __syncthreads();
        const unsigned tblk = s_tblk;
        if (tblk >= NBLK) break;           // uniform: all exit together
        const int tok = (int)tblk * 64 + lt;
        const int idx = x[tok];
        const f16x4 h = Wt[((size_t)slice * VOCAB + idx) * 4 + lq];
        f32x4 r;
        r.x = (float)h[0];
        r.y = (float)h[1];
        r.z = (float)h[2];
        r.w = (float)h[3];
        // byte offset tok*512 + slice*64 + lq*16: 4-lane group covers one
        // full 64 B line.
        out[(size_t)tok * 32 + slice * 4 + lq] = r;
        __syncthreads();                   // s_tblk reuse barrier
    }
}

// Fallback (ws too small): exact fp32 strided column gather.
__global__ void direct_kernel(const int* __restrict__ x,
                              const float* __restrict__ W,
                              const float* __restrict__ bias,
                              f32x4* __restrict__ out) {
    const int gid   = blockIdx.x * blockDim.x + threadIdx.x;
    const int token = gid >> 5;
    const int e4    = gid & 31;
    const int idx   = x[token];
    const int e     = e4 * 4;
    f32x4 r;
    r.x = W[(size_t)(e + 0) * VOCAB + idx] + bias[e + 0];
    r.y = W[(size_t)(e + 1) * VOCAB + idx] + bias[e + 1];
    r.z = W[(size_t)(e + 2) * VOCAB + idx] + bias[e + 2];
    r.w = W[(size_t)(e + 3) * VOCAB + idx] + bias[e + 3];
    out[(size_t)token * 32 + e4] = r;
}

extern "C" void kernel_launch(void* const* d_in, const int* in_sizes, int n_in,
                              void* d_out, int out_size, void* d_ws, size_t ws_size,
                              hipStream_t stream) {
    const int*   x    = (const int*)d_in[0];
    const float* W    = (const float*)d_in[1];
    const float* bias = (const float*)d_in[2];

    const size_t wt_bytes  = (size_t)VOCAB * EMBED * sizeof(_Float16); // 12.9 MB
    const size_t ctr_off   = (wt_bytes + 255) & ~(size_t)255;
    const size_t need      = ctr_off + NSLICE * sizeof(unsigned);

    if (ws_size >= need) {
        _Float16* Wt  = (_Float16*)d_ws;
        unsigned* ctr = (unsigned*)((char*)d_ws + ctr_off);

        zero_ctr_kernel<<<1, 64, 0, stream>>>(ctr);
        dim3 tgrid((VOCAB + 63) / 64, 2);   // 786 x 2 = 1572 blocks
        transpose_h_kernel<<<tgrid, 256, 0, stream>>>(W, bias, Wt);

        // 8192 blocks; each pulls work items for its own XCD's slice until
        // that slice's queue (4096 items) drains.
        gather_xcd_kernel<<<8192, 256, 0, stream>>>(x, (const f16x4*)Wt,
                                                    (f32x4*)d_out, ctr);
    } else {
        const int dblocks = (NTOK * 32) / 256;
        direct_kernel<<<dblocks, 256, 0, stream>>>(x, W, bias, (f32x4*)d_out);
    }
}

// Round 10
// 152.913 us; speedup vs baseline: 3.2154x; 3.2154x over previous
//
#include <hip/hip_runtime.h>
#include <hip/hip_cooperative_groups.h>

namespace cg = cooperative_groups;

#define VOCAB 50257
#define EMBED 128
#define NTOK  (64 * 4096)
#define NSLICE 8
#define NBLK  (NTOK / 64)      // 4096 token-blocks
#define NVB   (NBLK * NSLICE)  // 32768 gather work units
#define NTILE_V 786
#define NTILE (NTILE_V * 2)    // 1572 transpose tiles (64v x 64e)
#define NCU   256

typedef float    f32x4 __attribute__((ext_vector_type(4)));
typedef _Float16 f16x4 __attribute__((ext_vector_type(4)));
typedef _Float16 f16x8 __attribute__((ext_vector_type(8)));

// Fused: phase A transposes W into slice-major fp16 table (bias folded),
// grid-wide sync, phase B gathers. __launch_bounds__(256,8): cap VGPR at 64
// so 8 blocks/CU co-reside (cooperative-launch requirement).
__global__ void __launch_bounds__(256, 8)
fused_kernel(const int* __restrict__ x,
             const float* __restrict__ W,
             const float* __restrict__ bias,
             _Float16* __restrict__ Wt,
             f32x4* __restrict__ out) {
    __shared__ float tile[64][65];   // phase A only; +1 pad
    const int t    = threadIdx.x;
    const int bid  = blockIdx.x;
    const int grid = gridDim.x;      // multiple of 8 (host guarantees)

    // ---- Phase A: transpose (grid-stride over 1572 tiles) ----
    for (int tl = bid; tl < NTILE; tl += grid) {
        const int v0 = (tl % NTILE_V) * 64;
        const int e0 = (tl / NTILE_V) * 64;
        const bool full = (v0 + 64 <= VOCAB);

        if (full) {
#pragma unroll
            for (int it = 0; it < 4; ++it) {
                const int e_loc = (t >> 4) + it * 16;
                const int c4    = (t & 15) * 4;
                f32x4 val = *(const f32x4*)&W[(size_t)(e0 + e_loc) * VOCAB + v0 + c4];
                tile[c4 + 0][e_loc] = val.x;
                tile[c4 + 1][e_loc] = val.y;
                tile[c4 + 2][e_loc] = val.z;
                tile[c4 + 3][e_loc] = val.w;
            }
        } else {
#pragma unroll
            for (int it = 0; it < 16; ++it) {
                const int e_loc = (t >> 6) + it * 4;
                const int c     = t & 63;
                const int v     = v0 + c;
                tile[c][e_loc] = (v < VOCAB) ? W[(size_t)(e0 + e_loc) * VOCAB + v]
                                             : 0.0f;
            }
        }
        __syncthreads();

        const int eo = (t & 7) * 8;
        const int eg = e0 + eo;
        const int s  = eg >> 4;
        const int ep = eg & 15;
        const f32x4 ba = *(const f32x4*)&bias[eg];
        const f32x4 bb = *(const f32x4*)&bias[eg + 4];
#pragma unroll
        for (int it = 0; it < 2; ++it) {
            const int v_loc = (t >> 3) + it * 32;
            const int v     = v0 + v_loc;
            if (v < VOCAB) {
                f16x8 h;
                h[0] = (_Float16)(tile[v_loc][eo + 0] + ba.x);
                h[1] = (_Float16)(tile[v_loc][eo + 1] + ba.y);
                h[2] = (_Float16)(tile[v_loc][eo + 2] + ba.z);
                h[3] = (_Float16)(tile[v_loc][eo + 3] + ba.w);
                h[4] = (_Float16)(tile[v_loc][eo + 4] + bb.x);
                h[5] = (_Float16)(tile[v_loc][eo + 5] + bb.y);
                h[6] = (_Float16)(tile[v_loc][eo + 6] + bb.z);
                h[7] = (_Float16)(tile[v_loc][eo + 7] + bb.w);
                *(f16x8*)&Wt[((size_t)s * VOCAB + v) * 16 + ep] = h;
            }
        }
        __syncthreads();   // LDS reuse safety across loop iterations
    }

    // ---- grid-wide barrier: table complete ----
    cg::this_grid().sync();

    // ---- Phase B: sliced gather (grid-stride; slice fixed per block) ----
    const int slice = bid & (NSLICE - 1);   // stride ≡ 0 mod 8 keeps it fixed
    const int lq    = t & 3;
    const int lt    = t >> 2;
    const f16x4* Wts = (const f16x4*)Wt + (size_t)slice * VOCAB * 4;

    for (int vb = bid; vb < NVB; vb += grid) {
        const int tblk = vb >> 3;
        const int tok  = tblk * 64 + lt;
        const int idx  = x[tok];
        const f16x4 h  = Wts[(size_t)idx * 4 + lq];
        f32x4 r;
        r.x = (float)h[0];
        r.y = (float)h[1];
        r.z = (float)h[2];
        r.w = (float)h[3];
        out[(size_t)tok * 32 + slice * 4 + lq] = r;  // 4-lane group = full 64B line
    }
}

// ---- Proven two-kernel fallback (R7: 45.7 us) ----
__global__ void transpose_h_kernel(const float* __restrict__ W,
                                   const float* __restrict__ bias,
                                   _Float16* __restrict__ Wt) {
    __shared__ float tile[64][65];
    const int t  = threadIdx.x;
    const int v0 = blockIdx.x * 64;
    const int e0 = blockIdx.y * 64;
    const bool full = (v0 + 64 <= VOCAB);

    if (full) {
#pragma unroll
        for (int it = 0; it < 4; ++it) {
            const int e_loc = (t >> 4) + it * 16;
            const int c4    = (t & 15) * 4;
            f32x4 val = *(const f32x4*)&W[(size_t)(e0 + e_loc) * VOCAB + v0 + c4];
            tile[c4 + 0][e_loc] = val.x;
            tile[c4 + 1][e_loc] = val.y;
            tile[c4 + 2][e_loc] = val.z;
            tile[c4 + 3][e_loc] = val.w;
        }
    } else {
#pragma unroll
        for (int it = 0; it < 16; ++it) {
            const int e_loc = (t >> 6) + it * 4;
            const int c     = t & 63;
            const int v     = v0 + c;
            tile[c][e_loc] = (v < VOCAB) ? W[(size_t)(e0 + e_loc) * VOCAB + v]
                                         : 0.0f;
        }
    }
    __syncthreads();

    const int eo = (t & 7) * 8;
    const int eg = e0 + eo;
    const int s  = eg >> 4;
    const int ep = eg & 15;
    const f32x4 ba = *(const f32x4*)&bias[eg];
    const f32x4 bb = *(const f32x4*)&bias[eg + 4];
#pragma unroll
    for (int it = 0; it < 2; ++it) {
        const int v_loc = (t >> 3) + it * 32;
        const int v     = v0 + v_loc;
        if (v < VOCAB) {
            f16x8 h;
            h[0] = (_Float16)(tile[v_loc][eo + 0] + ba.x);
            h[1] = (_Float16)(tile[v_loc][eo + 1] + ba.y);
            h[2] = (_Float16)(tile[v_loc][eo + 2] + ba.z);
            h[3] = (_Float16)(tile[v_loc][eo + 3] + ba.w);
            h[4] = (_Float16)(tile[v_loc][eo + 4] + bb.x);
            h[5] = (_Float16)(tile[v_loc][eo + 5] + bb.y);
            h[6] = (_Float16)(tile[v_loc][eo + 6] + bb.z);
            h[7] = (_Float16)(tile[v_loc][eo + 7] + bb.w);
            *(f16x8*)&Wt[((size_t)s * VOCAB + v) * 16 + ep] = h;
        }
    }
}

__global__ void gather_sliced_kernel(const int* __restrict__ x,
                                     const f16x4* __restrict__ Wt,
                                     f32x4* __restrict__ out) {
    const int bid   = blockIdx.x;
    const int slice = bid & (NSLICE - 1);
    const int tblk  = bid >> 3;
    const int t     = threadIdx.x;
    const int tok   = tblk * 64 + (t >> 2);
    const int q     = t & 3;
    const int idx   = x[tok];
    const f16x4 h = Wt[((size_t)slice * VOCAB + idx) * 4 + q];
    f32x4 r;
    r.x = (float)h[0];
    r.y = (float)h[1];
    r.z = (float)h[2];
    r.w = (float)h[3];
    out[(size_t)tok * 32 + slice * 4 + q] = r;
}

__global__ void direct_kernel(const int* __restrict__ x,
                              const float* __restrict__ W,
                              const float* __restrict__ bias,
                              f32x4* __restrict__ out) {
    const int gid   = blockIdx.x * blockDim.x + threadIdx.x;
    const int token = gid >> 5;
    const int e4    = gid & 31;
    const int idx   = x[token];
    const int e     = e4 * 4;
    f32x4 r;
    r.x = W[(size_t)(e + 0) * VOCAB + idx] + bias[e + 0];
    r.y = W[(size_t)(e + 1) * VOCAB + idx] + bias[e + 1];
    r.z = W[(size_t)(e + 2) * VOCAB + idx] + bias[e + 2];
    r.w = W[(size_t)(e + 3) * VOCAB + idx] + bias[e + 3];
    out[(size_t)token * 32 + e4] = r;
}

extern "C" void kernel_launch(void* const* d_in, const int* in_sizes, int n_in,
                              void* d_out, int out_size, void* d_ws, size_t ws_size,
                              hipStream_t stream) {
    const int*   x    = (const int*)d_in[0];
    const float* W    = (const float*)d_in[1];
    const float* bias = (const float*)d_in[2];

    const size_t wt_bytes = (size_t)VOCAB * EMBED * sizeof(_Float16); // 12.9 MB

    if (ws_size < wt_bytes) {
        const int dblocks = (NTOK * 32) / 256;
        direct_kernel<<<dblocks, 256, 0, stream>>>(x, W, bias, (f32x4*)d_out);
        return;
    }

    _Float16* Wt = (_Float16*)d_ws;
    f32x4*    o  = (f32x4*)d_out;

    // Capture-safe occupancy query (no enqueue, no alloc).
    int blocks_per_cu = 0;
    hipError_t qerr = hipOccupancyMaxActiveBlocksPerMultiprocessor(
        &blocks_per_cu, (const void*)fused_kernel, 256, 0);

    if (qerr == hipSuccess && blocks_per_cu >= 1) {
        int grid = blocks_per_cu * NCU;        // multiple of 8 (NCU=256)
        if (grid > 2048) grid = 2048;
        void* args[] = {(void*)&x, (void*)&W, (void*)&bias, (void*)&Wt, (void*)&o};
        hipError_t lerr = hipLaunchCooperativeKernel(
            (const void*)fused_kernel, dim3(grid), dim3(256), args, 0, stream);
        if (lerr == hipSuccess) return;
    }

    // Fallback: proven R7 two-kernel path.
    dim3 tgrid((VOCAB + 63) / 64, 2);
    transpose_h_kernel<<<tgrid, 256, 0, stream>>>(W, bias, Wt);
    const int gblocks = (NTOK / 64) * NSLICE;
    gather_sliced_kernel<<<gblocks, 256, 0, stream>>>(x, (const f16x4*)Wt, o);
}

// Round 11
// 44.503 us; speedup vs baseline: 11.0480x; 3.4360x over previous
//
#include <hip/hip_runtime.h>

#define VOCAB 50257
#define EMBED 128
#define NTOK  (64 * 4096)
#define NSLICE 8            // 8 slices x 16 embed dims

typedef float    f32x4 __attribute__((ext_vector_type(4)));
typedef _Float16 f16x4 __attribute__((ext_vector_type(4)));
typedef _Float16 f16x8 __attribute__((ext_vector_type(8)));

// Pass 1: slice-major fp16 table with bias folded:
//   Wt[s][v][e'] = (half)(W[s*16+e'][v] + bias[s*16+e'])
// Tile 64v x 32e, grid=(786,4), block=256, LDS 8.4 KB. Shallow chains:
// 2 vector-load iters + 1 vector-store iter per block (latency-friendly).
__global__ void transpose_h_kernel(const float* __restrict__ W,
                                   const float* __restrict__ bias,
                                   _Float16* __restrict__ Wt) {
    __shared__ float tile[64][33];   // [v_loc][e_loc], +1 pad
    const int t  = threadIdx.x;
    const int v0 = blockIdx.x * 64;
    const int e0 = blockIdx.y * 32;
    const bool full = (v0 + 64 <= VOCAB);

    // Phase 1: load W[e0+e_loc][v0 + 4*(t&15) .. +3] as f32x4; 16 rows/iter.
    if (full) {
#pragma unroll
        for (int it = 0; it < 2; ++it) {
            const int e_loc = (t >> 4) + it * 16;
            const int c4    = (t & 15) * 4;
            f32x4 val = *(const f32x4*)&W[(size_t)(e0 + e_loc) * VOCAB + v0 + c4];
            tile[c4 + 0][e_loc] = val.x;
            tile[c4 + 1][e_loc] = val.y;
            tile[c4 + 2][e_loc] = val.z;
            tile[c4 + 3][e_loc] = val.w;
        }
    } else {
        // Tail v-block (v0 = 50240, 17 valid): guarded scalar loads.
#pragma unroll
        for (int it = 0; it < 8; ++it) {
            const int e_loc = (t >> 6) + it * 4;
            const int c     = t & 63;
            const int v     = v0 + c;
            tile[c][e_loc] = (v < VOCAB) ? W[(size_t)(e0 + e_loc) * VOCAB + v]
                                         : 0.0f;
        }
    }
    __syncthreads();

    // Phase 2: one f16x8 (16 B) store per thread into slice-major layout.
    // v_loc = t>>2 (0..63), eo = (t&3)*8 (0..24); eg = e0+eo.
    const int v_loc = t >> 2;
    const int eo    = (t & 3) * 8;
    const int eg    = e0 + eo;
    const int s     = eg >> 4;
    const int ep    = eg & 15;
    const int v     = v0 + v_loc;
    if (v < VOCAB) {
        const f32x4 ba = *(const f32x4*)&bias[eg];
        const f32x4 bb = *(const f32x4*)&bias[eg + 4];
        f16x8 h;
        h[0] = (_Float16)(tile[v_loc][eo + 0] + ba.x);
        h[1] = (_Float16)(tile[v_loc][eo + 1] + ba.y);
        h[2] = (_Float16)(tile[v_loc][eo + 2] + ba.z);
        h[3] = (_Float16)(tile[v_loc][eo + 3] + ba.w);
        h[4] = (_Float16)(tile[v_loc][eo + 4] + bb.x);
        h[5] = (_Float16)(tile[v_loc][eo + 5] + bb.y);
        h[6] = (_Float16)(tile[v_loc][eo + 6] + bb.z);
        h[7] = (_Float16)(tile[v_loc][eo + 7] + bb.w);
        *(f16x8*)&Wt[((size_t)s * VOCAB + v) * 16 + ep] = h;
    }
}

// Pass 2: sliced gather — IDENTICAL to R7 (45.7 us proven path).
__global__ void gather_sliced_kernel(const int* __restrict__ x,
                                     const f16x4* __restrict__ Wt,
                                     f32x4* __restrict__ out) {
    const int bid   = blockIdx.x;
    const int slice = bid & (NSLICE - 1);
    const int tblk  = bid >> 3;
    const int t     = threadIdx.x;
    const int tok   = tblk * 64 + (t >> 2);
    const int q     = t & 3;
    const int idx   = x[tok];
    const f16x4 h = Wt[((size_t)slice * VOCAB + idx) * 4 + q];
    f32x4 r;
    r.x = (float)h[0];
    r.y = (float)h[1];
    r.z = (float)h[2];
    r.w = (float)h[3];
    out[(size_t)tok * 32 + slice * 4 + q] = r;
}

// Fallback (ws too small): exact fp32 strided column gather.
__global__ void direct_kernel(const int* __restrict__ x,
                              const float* __restrict__ W,
                              const float* __restrict__ bias,
                              f32x4* __restrict__ out) {
    const int gid   = blockIdx.x * blockDim.x + threadIdx.x;
    const int token = gid >> 5;
    const int e4    = gid & 31;
    const int idx   = x[token];
    const int e     = e4 * 4;
    f32x4 r;
    r.x = W[(size_t)(e + 0) * VOCAB + idx] + bias[e + 0];
    r.y = W[(size_t)(e + 1) * VOCAB + idx] + bias[e + 1];
    r.z = W[(size_t)(e + 2) * VOCAB + idx] + bias[e + 2];
    r.w = W[(size_t)(e + 3) * VOCAB + idx] + bias[e + 3];
    out[(size_t)token * 32 + e4] = r;
}

extern "C" void kernel_launch(void* const* d_in, const int* in_sizes, int n_in,
                              void* d_out, int out_size, void* d_ws, size_t ws_size,
                              hipStream_t stream) {
    const int*   x    = (const int*)d_in[0];
    const float* W    = (const float*)d_in[1];
    const float* bias = (const float*)d_in[2];

    const size_t wt_bytes = (size_t)VOCAB * EMBED * sizeof(_Float16); // 12.9 MB

    if (ws_size >= wt_bytes) {
        _Float16* Wt = (_Float16*)d_ws;
        dim3 tgrid((VOCAB + 63) / 64, 4);   // 786 x 4 = 3144 blocks
        transpose_h_kernel<<<tgrid, 256, 0, stream>>>(W, bias, Wt);

        const int gblocks = (NTOK / 64) * NSLICE;   // 32768
        gather_sliced_kernel<<<gblocks, 256, 0, stream>>>(x, (const f16x4*)Wt,
                                                          (f32x4*)d_out);
    } else {
        const int dblocks = (NTOK * 32) / 256;
        direct_kernel<<<dblocks, 256, 0, stream>>>(x, W, bias, (f32x4*)d_out);
    }
}